// Round 8
// baseline (323.028 us; speedup 1.0000x reference)
//
#include <hip/hip_runtime.h>
#include <hip/hip_bf16.h>
#include <stdint.h>

#define OUT_CH 128
#define EPSV 1e-10f

typedef __attribute__((ext_vector_type(4))) float f32x4;
typedef __attribute__((ext_vector_type(8))) short bf16x8;

__device__ __forceinline__ ushort f2bf(float f) {
    union { float f; unsigned u; } a; a.f = f;
    unsigned u = a.u;
    unsigned r = (u + 0x7fffu + ((u >> 16) & 1u)) >> 16;  // RNE
    return (ushort)r;
}

__device__ __forceinline__ float bflo(unsigned u) { return __uint_as_float(u << 16); }
__device__ __forceinline__ float bfhi(unsigned u) { return __uint_as_float(u & 0xffff0000u); }

// ------ hist + one-time weight bf16 conversion + emb bf16 conversion (fused) ------
// blocks [0,HB): histogram of targets
// blocks [HB,HB+16): weight f32->bf16 into Wb (linear bf16 [256][128])
// blocks [HB+16, HB+16+EB): emb f32->bf16 into embb (std half of d_out)
__global__ __launch_bounds__(256) void hist_convert_kernel(
    const int* __restrict__ eidx, int* __restrict__ cnt, int E, int HB, int EB,
    const float* __restrict__ locw, const float* __restrict__ stdw,
    int4* __restrict__ Wb, const float* __restrict__ emb, int4* __restrict__ embb4)
{
    int b = blockIdx.x;
    if (b < HB) {
        int e = b * 256 + threadIdx.x;
        if (e < E) atomicAdd(&cnt[eidx[E + e]], 1);
    } else if (b < HB + 16) {
        int q = (b - HB) * 256 + threadIdx.x;   // 0..4095: 256 rows x 16 chunks
        int r = q >> 4;
        int c = q & 15;
        const float* src = (r < 128) ? (locw + r * 128 + c * 8)
                                     : (stdw + (r - 128) * 128 + c * 8);
        float4 u0 = *reinterpret_cast<const float4*>(src);
        float4 u1 = *reinterpret_cast<const float4*>(src + 4);
        unsigned p0 = (unsigned)f2bf(u0.x) | ((unsigned)f2bf(u0.y) << 16);
        unsigned p1 = (unsigned)f2bf(u0.z) | ((unsigned)f2bf(u0.w) << 16);
        unsigned p2 = (unsigned)f2bf(u1.x) | ((unsigned)f2bf(u1.y) << 16);
        unsigned p3 = (unsigned)f2bf(u1.z) | ((unsigned)f2bf(u1.w) << 16);
        Wb[q] = make_int4((int)p0, (int)p1, (int)p2, (int)p3);
    } else {
        int idx8 = (b - HB - 16) * 256 + threadIdx.x;   // one 8-float chunk
        const float4* e4 = (const float4*)emb;
        float4 u0 = e4[(size_t)idx8 * 2];
        float4 u1 = e4[(size_t)idx8 * 2 + 1];
        unsigned p0 = (unsigned)f2bf(u0.x) | ((unsigned)f2bf(u0.y) << 16);
        unsigned p1 = (unsigned)f2bf(u0.z) | ((unsigned)f2bf(u0.w) << 16);
        unsigned p2 = (unsigned)f2bf(u1.x) | ((unsigned)f2bf(u1.y) << 16);
        unsigned p3 = (unsigned)f2bf(u1.z) | ((unsigned)f2bf(u1.w) << 16);
        embb4[idx8] = make_int4((int)p0, (int)p1, (int)p2, (int)p3);
    }
}

__device__ __forceinline__ int block_exscan256(int v, int* lds, int* totalOut) {
    int t = threadIdx.x;
    lds[t] = v; __syncthreads();
    #pragma unroll
    for (int d = 1; d < 256; d <<= 1) {
        int x = (t >= d) ? lds[t - d] : 0;
        __syncthreads();
        lds[t] += x;
        __syncthreads();
    }
    int inc = lds[t];
    int tot = lds[255];
    __syncthreads();
    *totalOut = tot;
    return inc - v;
}

// block sums over 1024-element tiles
__global__ __launch_bounds__(256) void block_sum_kernel(
    const int* __restrict__ cnt, int* __restrict__ bsum, int N)
{
    __shared__ int lds[256];
    int base = blockIdx.x * 1024;
    int local = 0;
    #pragma unroll
    for (int k = 0; k < 4; ++k) {
        int idx = base + threadIdx.x * 4 + k;
        local += (idx < N) ? cnt[idx] : 0;
    }
    lds[threadIdx.x] = local; __syncthreads();
    for (int d = 128; d > 0; d >>= 1) {
        if (threadIdx.x < d) lds[threadIdx.x] += lds[threadIdx.x + d];
        __syncthreads();
    }
    if (threadIdx.x == 0) bsum[blockIdx.x] = lds[0];
}

// single-block exclusive scan of block sums (NB <= 256)
__global__ __launch_bounds__(256) void top_scan_kernel(
    const int* __restrict__ bsum, int* __restrict__ bofs, int NB)
{
    __shared__ int lds[256];
    int t = threadIdx.x;
    int v = (t < NB) ? bsum[t] : 0;
    int total;
    int ex = block_exscan256(v, lds, &total);
    if (t < NB) bofs[t] = ex;
}

// exclusive prefix -> cursor (start offsets); after fill, cursor = segment end
__global__ __launch_bounds__(256) void scan_final_kernel(
    const int* __restrict__ cnt, const int* __restrict__ bofs,
    int* __restrict__ cursor, int N)
{
    __shared__ int lds[256];
    int base = blockIdx.x * 1024;
    int c[4]; int local = 0;
    #pragma unroll
    for (int k = 0; k < 4; ++k) {
        int idx = base + threadIdx.x * 4 + k;
        c[k] = (idx < N) ? cnt[idx] : 0;
        local += c[k];
    }
    int total;
    int ex = block_exscan256(local, lds, &total);
    int run = bofs[blockIdx.x] + ex;
    #pragma unroll
    for (int k = 0; k < 4; ++k) {
        int idx = base + threadIdx.x * 4 + k;
        if (idx < N) { cursor[idx] = run; run += c[k]; }
    }
}

__global__ __launch_bounds__(256) void fill_kernel(
    const int* __restrict__ eidx, const float* __restrict__ enorm,
    int* __restrict__ cursor, int2* __restrict__ srcw, int E)
{
    int e = blockIdx.x * 256 + threadIdx.x;
    if (e >= E) return;
    int t = eidx[E + e];
    int s = eidx[e];
    float w = enorm[e];
    int pos = atomicAdd(&cursor[t], 1);
    srcw[pos] = make_int2(s, __float_as_int(w));
}

// ---------------- gather: segment-sum over bf16 emb into bf16 ptr rows ----------------
// Each 16-lane group owns TWO nodes (qa and qa+Nh) with fused edge loops:
// the joint min-loop unrolled x2 gives 4 independent srcw->emb load chains per
// thread. Lane owns 8 channels (16B uint4). bf16 ptr row r stored at 512B
// stride (first 256B) in the loc half (gemm-wave-exclusive region).
__global__ __launch_bounds__(256) void gather_kernel(
    const uint4* __restrict__ embb4, const int* __restrict__ cursor,
    const int* __restrict__ cnt, const int2* __restrict__ srcw,
    uint4* __restrict__ ptrb4, int N, int Nh)
{
    int idx = blockIdx.x * 256 + threadIdx.x;
    int qa = idx >> 4;
    if (qa >= Nh) return;
    int l16 = idx & 15;
    int qb = qa + Nh;
    bool hasB = qb < N;

    int ca = cnt[qa];
    int oa = cursor[qa] - ca;
    int cb = 0, ob = 0;
    if (hasB) { cb = cnt[qb]; ob = cursor[qb] - cb; }

    float a0=0.f,a1=0.f,a2=0.f,a3=0.f,a4=0.f,a5=0.f,a6=0.f,a7=0.f;
    float b0=0.f,b1=0.f,b2=0.f,b3=0.f,b4=0.f,b5=0.f,b6=0.f,b7=0.f;

    int m = ca < cb ? ca : cb;
    int j = 0;
    for (; j + 2 <= m; j += 2) {
        int2 pa0 = srcw[oa + j];
        int2 pa1 = srcw[oa + j + 1];
        int2 pb0 = srcw[ob + j];
        int2 pb1 = srcw[ob + j + 1];
        uint4 va0 = embb4[(size_t)pa0.x * 16 + l16];
        uint4 va1 = embb4[(size_t)pa1.x * 16 + l16];
        uint4 vb0 = embb4[(size_t)pb0.x * 16 + l16];
        uint4 vb1 = embb4[(size_t)pb1.x * 16 + l16];
        float wa0 = __int_as_float(pa0.y), wa1 = __int_as_float(pa1.y);
        float wb0 = __int_as_float(pb0.y), wb1 = __int_as_float(pb1.y);
        a0 += bflo(va0.x)*wa0 + bflo(va1.x)*wa1;  a1 += bfhi(va0.x)*wa0 + bfhi(va1.x)*wa1;
        a2 += bflo(va0.y)*wa0 + bflo(va1.y)*wa1;  a3 += bfhi(va0.y)*wa0 + bfhi(va1.y)*wa1;
        a4 += bflo(va0.z)*wa0 + bflo(va1.z)*wa1;  a5 += bfhi(va0.z)*wa0 + bfhi(va1.z)*wa1;
        a6 += bflo(va0.w)*wa0 + bflo(va1.w)*wa1;  a7 += bfhi(va0.w)*wa0 + bfhi(va1.w)*wa1;
        b0 += bflo(vb0.x)*wb0 + bflo(vb1.x)*wb1;  b1 += bfhi(vb0.x)*wb0 + bfhi(vb1.x)*wb1;
        b2 += bflo(vb0.y)*wb0 + bflo(vb1.y)*wb1;  b3 += bfhi(vb0.y)*wb0 + bfhi(vb1.y)*wb1;
        b4 += bflo(vb0.z)*wb0 + bflo(vb1.z)*wb1;  b5 += bfhi(vb0.z)*wb0 + bfhi(vb1.z)*wb1;
        b6 += bflo(vb0.w)*wb0 + bflo(vb1.w)*wb1;  b7 += bfhi(vb0.w)*wb0 + bfhi(vb1.w)*wb1;
    }
    for (; j < m; ++j) {
        int2 pa = srcw[oa + j];
        int2 pb = srcw[ob + j];
        uint4 va = embb4[(size_t)pa.x * 16 + l16];
        uint4 vb = embb4[(size_t)pb.x * 16 + l16];
        float wa = __int_as_float(pa.y), wb = __int_as_float(pb.y);
        a0 += bflo(va.x)*wa;  a1 += bfhi(va.x)*wa;
        a2 += bflo(va.y)*wa;  a3 += bfhi(va.y)*wa;
        a4 += bflo(va.z)*wa;  a5 += bfhi(va.z)*wa;
        a6 += bflo(va.w)*wa;  a7 += bfhi(va.w)*wa;
        b0 += bflo(vb.x)*wb;  b1 += bfhi(vb.x)*wb;
        b2 += bflo(vb.y)*wb;  b3 += bfhi(vb.y)*wb;
        b4 += bflo(vb.z)*wb;  b5 += bfhi(vb.z)*wb;
        b6 += bflo(vb.w)*wb;  b7 += bfhi(vb.w)*wb;
    }
    // tails (one of these runs)
    for (; j + 2 <= ca; j += 2) {
        int2 p0 = srcw[oa + j];
        int2 p1 = srcw[oa + j + 1];
        uint4 v0 = embb4[(size_t)p0.x * 16 + l16];
        uint4 v1 = embb4[(size_t)p1.x * 16 + l16];
        float w0 = __int_as_float(p0.y), w1 = __int_as_float(p1.y);
        a0 += bflo(v0.x)*w0 + bflo(v1.x)*w1;  a1 += bfhi(v0.x)*w0 + bfhi(v1.x)*w1;
        a2 += bflo(v0.y)*w0 + bflo(v1.y)*w1;  a3 += bfhi(v0.y)*w0 + bfhi(v1.y)*w1;
        a4 += bflo(v0.z)*w0 + bflo(v1.z)*w1;  a5 += bfhi(v0.z)*w0 + bfhi(v1.z)*w1;
        a6 += bflo(v0.w)*w0 + bflo(v1.w)*w1;  a7 += bfhi(v0.w)*w0 + bfhi(v1.w)*w1;
    }
    if (j < ca) {
        int2 p = srcw[oa + j];
        uint4 v = embb4[(size_t)p.x * 16 + l16];
        float w = __int_as_float(p.y);
        a0 += bflo(v.x)*w;  a1 += bfhi(v.x)*w;
        a2 += bflo(v.y)*w;  a3 += bfhi(v.y)*w;
        a4 += bflo(v.z)*w;  a5 += bfhi(v.z)*w;
        a6 += bflo(v.w)*w;  a7 += bfhi(v.w)*w;
    }
    for (j = m + ((ca - m) & ~0); false;) {}  // (no-op; clarity)
    for (j = (j > m ? j : m); j + 2 <= cb; j += 2) {
        int2 p0 = srcw[ob + j];
        int2 p1 = srcw[ob + j + 1];
        uint4 v0 = embb4[(size_t)p0.x * 16 + l16];
        uint4 v1 = embb4[(size_t)p1.x * 16 + l16];
        float w0 = __int_as_float(p0.y), w1 = __int_as_float(p1.y);
        b0 += bflo(v0.x)*w0 + bflo(v1.x)*w1;  b1 += bfhi(v0.x)*w0 + bfhi(v1.x)*w1;
        b2 += bflo(v0.y)*w0 + bflo(v1.y)*w1;  b3 += bfhi(v0.y)*w0 + bfhi(v1.y)*w1;
        b4 += bflo(v0.z)*w0 + bflo(v1.z)*w1;  b5 += bfhi(v0.z)*w0 + bfhi(v1.z)*w1;
        b6 += bflo(v0.w)*w0 + bflo(v1.w)*w1;  b7 += bfhi(v0.w)*w0 + bfhi(v1.w)*w1;
    }
    if (j < cb) {
        int2 p = srcw[ob + j];
        uint4 v = embb4[(size_t)p.x * 16 + l16];
        float w = __int_as_float(p.y);
        b0 += bflo(v.x)*w;  b1 += bfhi(v.x)*w;
        b2 += bflo(v.y)*w;  b3 += bfhi(v.y)*w;
        b4 += bflo(v.z)*w;  b5 += bfhi(v.z)*w;
        b6 += bflo(v.w)*w;  b7 += bfhi(v.w)*w;
    }

    uint4 ra;
    ra.x = (unsigned)f2bf(a0) | ((unsigned)f2bf(a1) << 16);
    ra.y = (unsigned)f2bf(a2) | ((unsigned)f2bf(a3) << 16);
    ra.z = (unsigned)f2bf(a4) | ((unsigned)f2bf(a5) << 16);
    ra.w = (unsigned)f2bf(a6) | ((unsigned)f2bf(a7) << 16);
    ptrb4[(size_t)qa * 32 + l16] = ra;
    if (hasB) {
        uint4 rb;
        rb.x = (unsigned)f2bf(b0) | ((unsigned)f2bf(b1) << 16);
        rb.y = (unsigned)f2bf(b2) | ((unsigned)f2bf(b3) << 16);
        rb.z = (unsigned)f2bf(b4) | ((unsigned)f2bf(b5) << 16);
        rb.w = (unsigned)f2bf(b6) | ((unsigned)f2bf(b7) << 16);
        ptrb4[(size_t)qb * 32 + l16] = rb;
    }
}

// ---------------- GEMM + bias + softplus, LDS-free single pass ----------------
// B-fragments loaded directly from global Wb (64KB, L1/L2-resident, shared by
// all blocks) -> no LDS, no barriers. One 16-row tile per wave, 64 rows/block.
// A (bf16 ptr, 512B row stride) lives in the loc half; each wave loads its 16
// rows into registers before any store (wave-exclusive in-place update).
__global__ __launch_bounds__(256, 4) void gemm_kernel(
    const ushort* __restrict__ Wbl, const float* __restrict__ locb,
    const float* __restrict__ stdb, float* __restrict__ out, int N)
{
    const int t = threadIdx.x;
    const int wave = t >> 6;
    const int lane = t & 63;
    const int grp = lane >> 4;
    const int l16 = lane & 15;
    const int base = blockIdx.x * 64 + wave * 16;

    const ushort* ptrb = (const ushort*)out;   // bf16 row r at ushort offset r*256
    int r0 = base + l16; if (r0 > N - 1) r0 = N - 1;

    bf16x8 a[4];
    #pragma unroll
    for (int s = 0; s < 4; ++s)
        a[s] = *reinterpret_cast<const bf16x8*>(ptrb + (size_t)r0 * 256 + s * 32 + grp * 8);

    f32x4 acc[16];
    #pragma unroll
    for (int j = 0; j < 16; ++j) acc[j] = (f32x4){0.f, 0.f, 0.f, 0.f};

    #pragma unroll
    for (int j = 0; j < 16; ++j) {
        int col = j * 16 + l16;                  // 0..255: loc cols then std cols
        const ushort* wrow = Wbl + col * 128 + grp * 8;
        #pragma unroll
        for (int s = 0; s < 4; ++s) {
            bf16x8 bfr = *reinterpret_cast<const bf16x8*>(wrow + s * 32);
            acc[j] = __builtin_amdgcn_mfma_f32_16x16x32_bf16(a[s], bfr, acc[j], 0, 0, 0);
        }
    }

    // C/D map: col = lane&15, row = grp*4 + reg (m89-verified)
    #pragma unroll
    for (int j = 0; j < 16; ++j) {
        int col = j * 16 + l16;
        bool isStd = col >= 128;
        int wcol = col & 127;
        float bias = isStd ? stdb[wcol] : locb[wcol];
        float* dst = isStd ? (out + (size_t)N * OUT_CH) : out;
        #pragma unroll
        for (int rg = 0; rg < 4; ++rg) {
            int node = base + grp * 4 + rg;
            if (node < N) {
                float x = acc[j][rg] + bias;
                if (isStd) x = __logf(1.0f + __expf(x)) + EPSV;  // |x| small: exact enough
                dst[(size_t)node * OUT_CH + wcol] = x;
            }
        }
    }
}

extern "C" void kernel_launch(void* const* d_in, const int* in_sizes, int n_in,
                              void* d_out, int out_size, void* d_ws, size_t ws_size,
                              hipStream_t stream) {
    const float* emb  = (const float*)d_in[0];
    const float* locw = (const float*)d_in[1];
    const float* locb = (const float*)d_in[2];
    const float* stdw = (const float*)d_in[3];
    const float* stdb = (const float*)d_in[4];
    const int*   eidx = (const int*)d_in[5];
    const float* enorm= (const float*)d_in[6];
    float* out = (float*)d_out;

    const int N = in_sizes[0] / OUT_CH;   // 100000
    const int E = in_sizes[6];            // 600000
    const int NB = (N + 1023) / 1024;     // 98 (<= 256 required)
    const int HB = (E + 255) / 256;       // 2344
    const int EB = (N * (OUT_CH / 8) + 255) / 256;  // emb 8-float chunks / 256
    const int Nh = (N + 1) / 2;           // 50000

    // workspace layout (~5.7 MB)
    int* cnt    = (int*)d_ws;            // N
    int* cursor = cnt + N;               // N
    int* bsum   = cursor + N;            // pad 256
    int* bofs   = bsum + 256;            // pad 256
    int2* srcw  = (int2*)(((uintptr_t)(bofs + 256) + 255) & ~(uintptr_t)255);  // E
    int4* Wb    = (int4*)(((uintptr_t)(srcw + E) + 255) & ~(uintptr_t)255);    // 64 KiB

    // bf16 emb lives in the std half of out (gemm overwrites it at the very end)
    unsigned* embb = (unsigned*)(out + (size_t)N * OUT_CH);

    hipMemsetAsync(cnt, 0, (size_t)N * sizeof(int), stream);

    hist_convert_kernel<<<HB + 16 + EB, 256, 0, stream>>>(
        eidx, cnt, E, HB, EB, locw, stdw, Wb, emb, (int4*)embb);
    block_sum_kernel<<<NB, 256, 0, stream>>>(cnt, bsum, N);
    top_scan_kernel<<<1, 256, 0, stream>>>(bsum, bofs, NB);
    scan_final_kernel<<<NB, 256, 0, stream>>>(cnt, bofs, cursor, N);
    fill_kernel<<<(E + 255) / 256, 256, 0, stream>>>(eidx, enorm, cursor, srcw, E);

    uint4* ptrb4 = (uint4*)out;   // bf16 ptr rows, 512B stride, loc half
    long gthreads = (long)Nh * 16;
    gather_kernel<<<(int)((gthreads + 255) / 256), 256, 0, stream>>>(
        (const uint4*)embb, cursor, cnt, srcw, ptrb4, N, Nh);

    int nblocks = (N + 63) / 64;
    gemm_kernel<<<nblocks, 256, 0, stream>>>((const ushort*)Wb, locb, stdb, out, N);
}